// Round 8
// baseline (239.383 us; speedup 1.0000x reference)
//
#include <hip/hip_runtime.h>

// Sparsemax along dim=-1 for [8192, 4096] fp32 — TWO-PASS structure.
//
// R2-R7 lesson: every single-pass design (regardless of inner structure)
// plateaued at 80-88 us with all pipes idle: the per-block serial chain
// {load row -> reduce -> Newton -> (re-read row) -> store row} is
// latency-bound, and the compiler refuses to keep the row in VGPRs across
// the solve (VGPR=24 in R7), forcing a re-read serialized behind Newton.
// Meanwhile the harness's own fillBuffer hit 6.8 TB/s (85% peak) in the same
// capture -- the chip streams fine; our dependency chain was the problem.
//
// Pass 1 (tau_kernel): one block/row, read + reduce + Newton over compacted
//   candidates, write ONE float (tau) to d_ws. No output stream behind the
//   solve. Pure-read floor ~21 us.
// Pass 2 (apply_kernel): pure streaming out = max(0, x - tau[row]). Input is
//   L3-resident after pass 1 (128 MiB < 256 MiB LLC); write-bound ~20 us at
//   the demonstrated fill BW. No barriers, no reductions, NT stores.
//
// Newton math (both passes exact): tau solves sum max(0, x - tau) = 1.
// tau0 = max-1; iterate tau <- (sum_{x>tau} x - 1)/|{x>tau}|. Monotone from
// below, support subset of {x > max-1} at every iterate, exact at fixed
// point. Candidate compaction (~14/4096 for Gaussian rows) with full-row
// fallback if >CAND_CAP candidates (adversarial data only).

#define COLS 4096
#define THREADS 256
#define NW 4
#define CAND_CAP 1024
#define MAX_ITERS 32
#define APPLY_ROWS 4  // rows per apply block

typedef float f32x4 __attribute__((ext_vector_type(4)));

__global__ __launch_bounds__(THREADS) void tau_kernel(
    const float* __restrict__ x, float* __restrict__ taus, int rows) {
  __shared__ float cand[CAND_CAP];
  __shared__ float wred[NW];
  __shared__ int wcnt_s[NW];
  __shared__ int cnt;

  const int tid = threadIdx.x;
  const int lane = tid & 63;
  const int wid = tid >> 6;
  const long row = blockIdx.x;
  if (row >= rows) return;

  const f32x4* __restrict__ xr =
      reinterpret_cast<const f32x4*>(x + row * COLS);

  if (tid == 0) cnt = 0;

  // Thread t owns float4 slots {t, t+256, t+512, t+768}: fully coalesced.
  f32x4 v0 = xr[tid];
  f32x4 v1 = xr[tid + THREADS];
  f32x4 v2 = xr[tid + 2 * THREADS];
  f32x4 v3 = xr[tid + 3 * THREADS];

  // Row max: per-thread tree -> wave butterfly -> cross-wave via LDS.
  float m = fmaxf(fmaxf(v0.x, v0.y), fmaxf(v0.z, v0.w));
  m = fmaxf(m, fmaxf(fmaxf(v1.x, v1.y), fmaxf(v1.z, v1.w)));
  m = fmaxf(m, fmaxf(fmaxf(v2.x, v2.y), fmaxf(v2.z, v2.w)));
  m = fmaxf(m, fmaxf(fmaxf(v3.x, v3.y), fmaxf(v3.z, v3.w)));
#pragma unroll
  for (int off = 32; off > 0; off >>= 1) m = fmaxf(m, __shfl_xor(m, off));
  if (lane == 0) wred[wid] = m;
  __syncthreads();
  m = fmaxf(fmaxf(wred[0], wred[1]), fmaxf(wred[2], wred[3]));

  const float thr = m - 1.0f;

  // Compact candidates (x > max-1) into LDS: support subset of candidates at
  // every Newton iterate (tau >= max-1 always) -> filtered sums exact.
#define EMIT(val)                          \
  if ((val) > thr) {                       \
    int p = atomicAdd(&cnt, 1);            \
    if (p < CAND_CAP) cand[p] = (val);     \
  }
  EMIT(v0.x) EMIT(v0.y) EMIT(v0.z) EMIT(v0.w)
  EMIT(v1.x) EMIT(v1.y) EMIT(v1.z) EMIT(v1.w)
  EMIT(v2.x) EMIT(v2.y) EMIT(v2.z) EMIT(v2.w)
  EMIT(v3.x) EMIT(v3.y) EMIT(v3.z) EMIT(v3.w)
#undef EMIT
  __syncthreads();
  const int nc = cnt;

  float tau = thr;
  if (nc <= CAND_CAP) {
    // Fast path: wave 0 solves over the tiny candidate set (others idle into
    // the exit; no barriers needed below this point).
    if (wid == 0) {
      for (int it = 0; it < MAX_ITERS; ++it) {
        float s = 0.0f;
        int c = 0;
        for (int k = lane; k < nc; k += 64) {
          float q = cand[k];
          if (q > tau) { s += q; c += 1; }
        }
#pragma unroll
        for (int off = 32; off > 0; off >>= 1) {
          s += __shfl_xor(s, off);
          c += __shfl_xor(c, off);
        }
        float ntau = (s - 1.0f) / (float)c;  // c>=1: max elem in support
        if (ntau == tau) break;              // wave-uniform fixed point
        tau = ntau;
      }
      if (lane == 0) taus[row] = tau;
    }
  } else {
    // Fallback (adversarial inputs only): block-wide Newton on register data.
    for (int it = 0; it < MAX_ITERS; ++it) {
      float s = 0.0f;
      int c = 0;
#define ACC(val) if ((val) > tau) { s += (val); c += 1; }
      ACC(v0.x) ACC(v0.y) ACC(v0.z) ACC(v0.w)
      ACC(v1.x) ACC(v1.y) ACC(v1.z) ACC(v1.w)
      ACC(v2.x) ACC(v2.y) ACC(v2.z) ACC(v2.w)
      ACC(v3.x) ACC(v3.y) ACC(v3.z) ACC(v3.w)
#undef ACC
#pragma unroll
      for (int off = 32; off > 0; off >>= 1) {
        s += __shfl_xor(s, off);
        c += __shfl_xor(c, off);
      }
      if (lane == 0) { wred[wid] = s; wcnt_s[wid] = c; }
      __syncthreads();
      s = wred[0] + wred[1] + wred[2] + wred[3];
      c = wcnt_s[0] + wcnt_s[1] + wcnt_s[2] + wcnt_s[3];
      float ntau = (s - 1.0f) / (float)c;
      __syncthreads();
      if (ntau == tau) break;  // block-uniform
      tau = ntau;
    }
    if (tid == 0) taus[row] = tau;
  }
}

// Pure streaming: out = max(0, x - tau[row]). 4 rows per block; tau loads are
// block-uniform (scalar). Input is L3-resident from pass 1; NT stores for the
// write-once output.
__global__ __launch_bounds__(THREADS) void apply_kernel(
    const float* __restrict__ x, const float* __restrict__ taus,
    float* __restrict__ out) {
  const long base_row = (long)blockIdx.x * APPLY_ROWS;
  const float t0 = taus[base_row + 0];
  const float t1 = taus[base_row + 1];
  const float t2 = taus[base_row + 2];
  const float t3 = taus[base_row + 3];

  const f32x4* __restrict__ xr =
      reinterpret_cast<const f32x4*>(x + base_row * COLS);
  f32x4* __restrict__ outr = reinterpret_cast<f32x4*>(out + base_row * COLS);
  const int tid = threadIdx.x;

#pragma unroll
  for (int k = 0; k < 16; ++k) {
    // Block region = 4096 float4s; index tid + k*256; row = k/4 (compile-time).
    const float tk = (k < 4) ? t0 : (k < 8) ? t1 : (k < 12) ? t2 : t3;
    f32x4 v = xr[tid + k * THREADS];
    f32x4 o;
    o.x = fmaxf(v.x - tk, 0.0f);
    o.y = fmaxf(v.y - tk, 0.0f);
    o.z = fmaxf(v.z - tk, 0.0f);
    o.w = fmaxf(v.w - tk, 0.0f);
    __builtin_nontemporal_store(o, outr + tid + k * THREADS);
  }
}

extern "C" void kernel_launch(void* const* d_in, const int* in_sizes, int n_in,
                              void* d_out, int out_size, void* d_ws,
                              size_t ws_size, hipStream_t stream) {
  const float* x = (const float*)d_in[0];
  float* out = (float*)d_out;
  float* taus = (float*)d_ws;  // rows floats; ws re-poisoned each call, we
                               // fully overwrite before reading
  const int rows = in_sizes[0] / COLS;  // 8192
  tau_kernel<<<rows, THREADS, 0, stream>>>(x, taus, rows);
  apply_kernel<<<rows / APPLY_ROWS, THREADS, 0, stream>>>(x, taus, out);
}